// Round 6
// baseline (612.623 us; speedup 1.0000x reference)
//
#include <hip/hip_runtime.h>
#include <hip/hip_bf16.h>
#include <stdint.h>
#include <stddef.h>

typedef unsigned short ushort_t;
typedef unsigned int uint_t;

typedef __attribute__((ext_vector_type(8))) short short8;
typedef __attribute__((ext_vector_type(4))) float floatx4;
typedef __attribute__((ext_vector_type(16))) float floatx16;
typedef __attribute__((ext_vector_type(4))) uint_t uintx4;

#define N_ROWS 32768
#define K_ENT  8192
#define CDIM   256
#define OUT_ELEMS 8388608
#define LOSS_OFF  8388608
#define IDX_OFF   8388609
// Per-(row, k-quarter) survivor list capacity. The two eighth-waves of a
// quarter share one list + one live (LDS) running max, so appends ~= a single
// interleaved 2048-entry scan ~= 20 (permutation-invariant); CAP_Q=44 keeps
// overflow at ~1e-5 kernel-wide.
#define CAP_Q  44
// Margin: covers bf16 rounding of z,c + reference fp32 quantization ulp(256).
// Refine re-filters stored candidates against the FINAL row max (max of stored
// vals). Every per-lane threshold is <= final_max - MARGIN (local and shared
// maxes never exceed the final max), so the stored set is always a superset of
// {entries within MARGIN of the final max} regardless of cross-wave timing.
#define MARGIN    2.0e-4f

// RNE float -> bf16 bits
__device__ __forceinline__ ushort_t f2bf(float f) {
    uint_t x = __float_as_uint(f);
    uint_t r = (x + 0x7fffu + ((x >> 16) & 1u)) >> 16;
    return (ushort_t)r;
}

// Sortable-uint encoding of float (monotone for all reals, either sign)
__device__ __forceinline__ uint_t fkey(float v) {
    uint_t b = __float_as_uint(v);
    return b ^ (uint_t)(((int)b >> 31) | 0x80000000);
}
__device__ __forceinline__ float finv(uint_t k) {
    uint_t b = (k & 0x80000000u) ? (k ^ 0x80000000u) : ~k;
    return __uint_as_float(b);
}

// Swizzled layout for mfma_32x32x16 fragments: element (row, c) lives at
//   (row>>5)*8192 + (c>>4)*512 + ((c>>3)&1)*256 + (row&31)*8 + (c&7)   [ushort idx]
// -> fragment load for k-step s (lane l: row r0+(l&31), dims s*16+(l>>5)*8, 16 B)
//    is one contiguous 1 KiB per (rowgroup, s); a 32-ent tile is 16 KB contiguous
//    and LINEAR -> global_load_lds(16B) staging works with a linear LDS dest.

__device__ __forceinline__ void gload_lds16(const ushort_t* g, ushort_t* s) {
    __builtin_amdgcn_global_load_lds(
        (__attribute__((address_space(1))) void*)(g),
        (__attribute__((address_space(3))) void*)(s), 16, 0, 0);
}

// Fused prep: blocks [0,2048) transpose z -> swizzled bf16 (+ fp32 ztf copy);
// blocks [2048,3072) pack codebook -> swizzled bf16 and init cnt/cnt2/acc.
__global__ __launch_bounds__(256) void k_prep(const float* __restrict__ zin,
                                              const float* __restrict__ cb,
                                              ushort_t* __restrict__ zsw,
                                              ushort_t* __restrict__ cbsw,
                                              float* __restrict__ ztf,
                                              int* __restrict__ cnt,
                                              int* __restrict__ cnt2,
                                              double* __restrict__ acc) {
    int bid = blockIdx.x;
    if (bid >= 2048) {
        int t = (bid - 2048) * 256 + threadIdx.x;   // 262,144 items
        if (t < N_ROWS * 4) cnt[t] = 0;
        if (t == 0) { *acc = 0.0; *cnt2 = 0; }
        int ent = t >> 5;
        int c0  = (t & 31) << 3;
        const float* p = cb + (size_t)ent * CDIM + c0;
        floatx4 f0 = *(const floatx4*)p;
        floatx4 f1 = *(const floatx4*)(p + 4);
        uintx4 pk;
        pk[0] = (uint_t)f2bf(f0[0]) | ((uint_t)f2bf(f0[1]) << 16);
        pk[1] = (uint_t)f2bf(f0[2]) | ((uint_t)f2bf(f0[3]) << 16);
        pk[2] = (uint_t)f2bf(f1[0]) | ((uint_t)f2bf(f1[1]) << 16);
        pk[3] = (uint_t)f2bf(f1[2]) | ((uint_t)f2bf(f1[3]) << 16);
        int idx = (ent >> 5) * 8192 + (c0 >> 4) * 512 + ((c0 >> 3) & 1) * 256 + (ent & 31) * 8;
        *(uintx4*)(cbsw + idx) = pk;
        return;
    }
    __shared__ float lds[64][65];
    int c0 = (bid & 3) << 6;
    int s0 = ((bid >> 2) & 63) << 6;
    int b  = bid >> 8;
    int tid = threadIdx.x;
    int j = tid & 63, ib = tid >> 6;
    const float* zb = zin + ((size_t)b << 20);
#pragma unroll
    for (int rr = 0; rr < 16; ++rr) {
        int i = rr * 4 + ib;                       // c-local
        lds[i][j] = zb[(size_t)(c0 + i) * 4096 + s0 + j];   // coalesced over j
    }
    __syncthreads();
#pragma unroll
    for (int it = 0; it < 2; ++it) {
        int item = it * 256 + tid;                 // 512 items: (s-local, c-chunk)
        int sl = item >> 3;
        int ch = item & 7;
        int row = (b << 12) + s0 + sl;             // n
        int cg  = c0 + ch * 8;
        uintx4 pk;
        floatx4 f0, f1;
#pragma unroll
        for (int q = 0; q < 4; ++q) {
            float a = lds[ch * 8 + 2 * q][sl];
            float bqv = lds[ch * 8 + 2 * q + 1][sl];
            pk[q] = (uint_t)f2bf(a) | ((uint_t)f2bf(bqv) << 16);
        }
#pragma unroll
        for (int q = 0; q < 4; ++q) {
            f0[q] = lds[ch * 8 + q][sl];
            f1[q] = lds[ch * 8 + 4 + q][sl];
        }
        int idx = (row >> 5) * 8192 + (cg >> 4) * 512 + ((cg >> 3) & 1) * 256 + (row & 31) * 8;
        *(uintx4*)(zsw + idx) = pk;
        if (ztf) {
            *(floatx4*)(ztf + (size_t)row * 256 + cg) = f0;
            *(floatx4*)(ztf + (size_t)row * 256 + cg + 4) = f1;
        }
    }
}

// Per-tile max-reduce + survivor append with LDS-shared state (ROUND 6):
// threshold = max(local running max incl. this tile, stale shared max) - M;
// shared max updated with fire-and-forget LDS atomicMax (sortable-uint key);
// slots allocated per-lane via LDS atomicAdd (on-chip, ~no latency exposure,
// shared across the quarter's two eighth-waves). Stores fire-and-forget.
// C/D layout (32x32x16): col(z-row)=lane&31, ent=(r&3)+8*(r>>2)+4*(l>>5).
__device__ __forceinline__ void screen_emit(const floatx16& acc, float& rml,
                                            uint_t stale_key, uint_t* rmx_u,
                                            int* cnt_sh, int r, int2* slist,
                                            int ent0) {
    float t0 = fmaxf(fmaxf(acc[0], acc[1]), fmaxf(acc[2], acc[3]));
    float t1 = fmaxf(fmaxf(acc[4], acc[5]), fmaxf(acc[6], acc[7]));
    float t2 = fmaxf(fmaxf(acc[8], acc[9]), fmaxf(acc[10], acc[11]));
    float t3 = fmaxf(fmaxf(acc[12], acc[13]), fmaxf(acc[14], acc[15]));
    float mx = fmaxf(fmaxf(t0, t1), fmaxf(t2, t3));
    mx = fmaxf(mx, __shfl_xor(mx, 32));   // other lane-half holds other 16 ents
    rml = fmaxf(rml, mx);
    atomicMax(&rmx_u[r], fkey(mx));       // publish (no return dependency)
    float thr = fmaxf(rml, finv(stale_key)) - MARGIN;
    uint_t mask = 0u;
#pragma unroll
    for (int i = 0; i < 16; ++i)
        if (acc[i] >= thr) mask |= (1u << i);
    if (mask) {
        int s = atomicAdd(&cnt_sh[r], __popc(mask));   // LDS atomic (fast)
#pragma unroll
        for (int i = 0; i < 16; ++i) {
            if (mask & (1u << i)) {
                if (s < CAP_Q)
                    slist[s] = make_int2(ent0 + (i & 3) + 8 * (i >> 2),
                                         __float_as_int(acc[i]));
                ++s;
            }
        }
    }
}

// SINGLE-PASS bf16 MFMA screen, 32x32x16, entries on the accumulator register
// axis, z-rows on the lane axis. ROUND 6: k-EIGHTH waves x 64 rows. Block =
// 512 threads = 8 waves = (4 row-subgroups x 2 eighths) covering 256 rows x 1
// quarter. 64-row waves halve DS demand per MFMA (each frag read feeds 2
// MFMAs); the eighth split doubles the wave count back to 4096 -> 16 waves/CU
// (R2/R5's occupancy trap avoided). The quarter's two eighth-waves share the
// row's survivor list + live max + slot counter via LDS atomics, so surv
// memory is unchanged. kt count halves to 32 -> half the barrier convoys.
// Per-dot accumulation order (s=0..15 within tile) is bit-identical to R4.
__global__ __launch_bounds__(512, 4) void k_screen(const ushort_t* __restrict__ zsw,
                                                   const ushort_t* __restrict__ cbsw,
                                                   int2* __restrict__ surv,
                                                   int* __restrict__ cnt) {
    __shared__ ushort_t bt[4][8192];    // [eighth*2 + buf] 16 KB tiles = 64 KB
    __shared__ uint_t rmx_u[256];       // live per-row max (sortable-uint)
    __shared__ int cnt_sh[256];         // live per-row append counter
    int tid = threadIdx.x;              // 0..511
    int w = tid >> 6, l = tid & 63;
    int e = w & 1, rsub = w >> 1;       // eighth, row-subgroup (0..3)
    int bid = blockIdx.x;
    int q  = bid & 3;                   // quarter (XCD x&3 -> L2-pinned 1 MB)
    int RB = (bid >> 2) * 256;          // block row base
    int tg0 = q * 64 + e * 32;          // wave's first global 32-ent tile

    if (tid < 256) { rmx_u[tid] = fkey(-3.0e38f); cnt_sh[tid] = 0; }

    // prologue: stage tile 0 of both eighths (wave w: eighth e, 4 KB portion rsub)
    {
        const ushort_t* gsrc = cbsw + (size_t)tg0 * 8192 + rsub * 2048;
        ushort_t* ldst = &bt[e * 2 + 0][rsub * 2048];
#pragma unroll
        for (int j = 0; j < 4; ++j)
            gload_lds16(gsrc + j * 512 + l * 8, ldst + j * 512);
    }

    // z fragments for both 32-row groups (B operand), in regs all kernel
    short8 zfr0[16], zfr1[16];
    {
        const ushort_t* pz = zsw + (size_t)((RB >> 5) + rsub * 2) * 8192 + l * 8;
#pragma unroll
        for (int s = 0; s < 16; ++s) {
            zfr0[s] = *(const short8*)(pz + s * 512);
            zfr1[s] = *(const short8*)(pz + 8192 + s * 512);
        }
    }

    int r0 = rsub * 64 + (l & 31);      // local row (acc0); acc1 rows: +32
    int n0 = RB + r0;
    int2* sl0 = surv + (size_t)(n0 * 4 + q) * CAP_Q;
    int2* sl1 = surv + (size_t)((n0 + 32) * 4 + q) * CAP_Q;
    float rml0 = -3.0e38f, rml1 = -3.0e38f;
    int esub = (l >> 5) * 4;            // C/D ent = (i&3) + 8*(i>>2) + 4*(l>>5)
    __syncthreads();

    for (int kt = 0; kt < 32; ++kt) {
        // stale shared maxes (any old value is a correct, conservative bound)
        uint_t sk0 = rmx_u[r0];
        uint_t sk1 = rmx_u[r0 + 32];

        // prefetch next tile into other buffer (last iter re-stages tile 0)
        {
            int nb = (kt + 1) & 1, ntt = (kt + 1) & 31;
            const ushort_t* gsrc = cbsw + (size_t)(tg0 + ntt) * 8192 + rsub * 2048;
            ushort_t* ldst = &bt[e * 2 + nb][rsub * 2048];
#pragma unroll
            for (int j = 0; j < 4; ++j)
                gload_lds16(gsrc + j * 512 + l * 8, ldst + j * 512);
        }

        const ushort_t* bb = &bt[e * 2 + (kt & 1)][l * 8];
        floatx16 acc0, acc1;
#pragma unroll
        for (int i = 0; i < 16; ++i) { acc0[i] = 0.f; acc1[i] = 0.f; }
        __builtin_amdgcn_s_setprio(1);
#pragma unroll
        for (int s = 0; s < 16; ++s) {
            short8 a = *(const short8*)(bb + s * 512);   // codebook frag (A: ents)
            acc0 = __builtin_amdgcn_mfma_f32_32x32x16_bf16(a, zfr0[s], acc0, 0, 0, 0);
            acc1 = __builtin_amdgcn_mfma_f32_32x32x16_bf16(a, zfr1[s], acc1, 0, 0, 0);
        }
        __builtin_amdgcn_s_setprio(0);

        int ent0 = (tg0 + kt) * 32 + esub;
        screen_emit(acc0, rml0, sk0, rmx_u, cnt_sh, r0,      sl0, ent0);
        screen_emit(acc1, rml1, sk1, rmx_u, cnt_sh, r0 + 32, sl1, ent0);
        __syncthreads();                // next tiles staged, buffers reusable
    }
    if (tid < 256) cnt[(RB + tid) * 4 + q] = cnt_sh[tid];
}

// Exact fp32 refine: gather <=176 stored (ent, bf16-dot) candidates from the 4
// quarter lists, filter by val >= finalmax - MARGIN (finalmax = max stored val;
// the record-setter always self-appends), then fp32 dots for the ~1-3 passing
// candidates. Serial fmaf order unchanged, so idx semantics are unchanged.
// Overflow (~1e-5 probability) -> 4-chain fast full-scan fallback.
__global__ __launch_bounds__(256) void k_refine(const float* __restrict__ zin,
                                                const float* __restrict__ ztf,
                                                const float* __restrict__ cb,
                                                const int2* __restrict__ surv,
                                                const int* __restrict__ cnt,
                                                int* __restrict__ idxi,
                                                float* __restrict__ idxf) {
    __shared__ float zr[4][256];
    int w = threadIdx.x >> 6, l = threadIdx.x & 63;
    int n = blockIdx.x * 4 + w;
    if (ztf) {
        const float* zrow = ztf + (size_t)n * 256;
#pragma unroll
        for (int i = 0; i < 4; ++i)
            zr[w][l + 64 * i] = zrow[l + 64 * i];          // coalesced
    } else {
        int b = n >> 12, s = n & 4095;
        const float* zb = zin + ((size_t)b << 20) + s;
#pragma unroll
        for (int i = 0; i < 4; ++i)
            zr[w][l + 64 * i] = zb[(size_t)(l + 64 * i) << 12];
    }
    __syncthreads();
    const float* z = zr[w];
    float zn = 0.f;
    for (int c = 0; c < 256; ++c) zn = fmaf(z[c], z[c], zn);

    int c0 = cnt[n * 4 + 0], c1 = cnt[n * 4 + 1];
    int c2 = cnt[n * 4 + 2], c3 = cnt[n * 4 + 3];
    int m = c0 + c1 + c2 + c3;
    bool ok = (c0 <= CAP_Q) && (c1 <= CAP_Q) && (c2 <= CAP_Q) && (c3 <= CAP_Q) && (m >= 1);
    float bu = 3.0e38f;
    int bk = 0x7fffffff;
    if (ok) {
        int myk[3]; float myv[3]; int nc = 0;
        float vmax = -3.0e38f;
        for (int i = l; i < m; i += 64) {
            int qq, s;
            if (i < c0)            { qq = 0; s = i; }
            else if (i < c0 + c1)  { qq = 1; s = i - c0; }
            else if (i < c0 + c1 + c2) { qq = 2; s = i - c0 - c1; }
            else                   { qq = 3; s = i - c0 - c1 - c2; }
            int2 kv = surv[(n * 4 + qq) * CAP_Q + s];
            myk[nc] = kv.x;
            myv[nc] = __int_as_float(kv.y);
            vmax = fmaxf(vmax, myv[nc]);
            ++nc;
        }
#pragma unroll
        for (int msk = 1; msk < 64; msk <<= 1)
            vmax = fmaxf(vmax, __shfl_xor(vmax, msk));
        float fthr = vmax - MARGIN;
        for (int jj = 0; jj < nc; ++jj) {
            if (myv[jj] >= fthr) {
                int k = myk[jj];
                const float* cr = cb + (size_t)k * 256;
                float d = 0.f;
                for (int c = 0; c < 256; c += 4) {
                    floatx4 wv = *(const floatx4*)(cr + c);
                    d = fmaf(z[c], wv[0], d);
                    d = fmaf(z[c + 1], wv[1], d);
                    d = fmaf(z[c + 2], wv[2], d);
                    d = fmaf(z[c + 3], wv[3], d);
                }
                float u = zn - 2.0f * d;
                if (u < bu || (u == bu && k < bk)) { bu = u; bk = k; }
            }
        }
    } else {
        // fallback: exact scan of all K with 4 independent chains (cold path)
        for (int kb = l; kb < K_ENT; kb += 256) {
            const float* p0 = cb + (size_t)(kb)       * 256;
            const float* p1 = cb + (size_t)(kb + 64)  * 256;
            const float* p2 = cb + (size_t)(kb + 128) * 256;
            const float* p3 = cb + (size_t)(kb + 192) * 256;
            float d0 = 0.f, d1 = 0.f, d2 = 0.f, d3 = 0.f;
            for (int c = 0; c < 256; c += 4) {
                floatx4 w0 = *(const floatx4*)(p0 + c);
                floatx4 w1 = *(const floatx4*)(p1 + c);
                floatx4 w2 = *(const floatx4*)(p2 + c);
                floatx4 w3 = *(const floatx4*)(p3 + c);
#pragma unroll
                for (int j = 0; j < 4; ++j) {
                    d0 = fmaf(z[c + j], w0[j], d0);
                    d1 = fmaf(z[c + j], w1[j], d1);
                    d2 = fmaf(z[c + j], w2[j], d2);
                    d3 = fmaf(z[c + j], w3[j], d3);
                }
            }
            float u0 = zn - 2.0f * d0, u1 = zn - 2.0f * d1;
            float u2 = zn - 2.0f * d2, u3 = zn - 2.0f * d3;
            // ascending k order preserves first-index tie-break
            if (u0 < bu) { bu = u0; bk = kb; }
            if (u1 < bu) { bu = u1; bk = kb + 64; }
            if (u2 < bu) { bu = u2; bk = kb + 128; }
            if (u3 < bu) { bu = u3; bk = kb + 192; }
        }
    }
#pragma unroll
    for (int msk = 1; msk < 64; msk <<= 1) {
        float ou = __shfl_xor(bu, msk);
        int   ok2 = __shfl_xor(bk, msk);
        if (ou < bu || (ou == bu && ok2 < bk)) { bu = ou; bk = ok2; }
    }
    if (l == 0) { idxi[n] = bk; idxf[n] = (float)bk; }
}

// Gather z_q + loss (coalesced codebook reads via LDS transpose), with fused
// last-block loss finalization (device-scope atomics + threadfence).
__global__ __launch_bounds__(256) void k_gather(const float* __restrict__ zin,
                                                const float* __restrict__ cb,
                                                const int* __restrict__ idxi,
                                                float* __restrict__ out,
                                                double* __restrict__ acc,
                                                int* __restrict__ cnt2) {
    __shared__ float tile[64][65];
    __shared__ int lk[64];
    __shared__ float wsum[4];
    int t = threadIdx.x;
    int blk = blockIdx.x;
    int b = blk >> 6;
    int s0 = (blk & 63) << 6;
    int n0 = (b << 12) + s0;
    if (t < 64) lk[t] = idxi[n0 + t];
    __syncthreads();
    int wv = t >> 6, ln = t & 63;
    float ls = 0.f;
#pragma unroll
    for (int ct = 0; ct < 4; ++ct) {
        int c0 = ct << 6;
#pragma unroll
        for (int i = 0; i < 16; ++i) {
            int sl = (wv << 4) + i;
            tile[sl][ln] = cb[(size_t)lk[sl] * 256 + c0 + ln];   // 256 B coalesced
        }
        __syncthreads();
        const float* zb = zin + ((size_t)b << 20);
        float* ob = out + ((size_t)b << 20);
#pragma unroll
        for (int j = 0; j < 16; ++j) {
            int cl = (wv << 4) + j;
            size_t o = (size_t)(c0 + cl) * 4096 + s0 + ln;
            float v = tile[ln][cl];       // stride-65: 2-way bank alias (free)
            float zv = zb[o];
            ob[o] = v;
            float d = v - zv;
            ls = fmaf(d, d, ls);
        }
        __syncthreads();
    }
#pragma unroll
    for (int msk = 1; msk < 64; msk <<= 1) ls += __shfl_xor(ls, msk);
    if (ln == 0) wsum[wv] = ls;
    __syncthreads();
    if (t == 0) {
        float tot = (wsum[0] + wsum[1]) + (wsum[2] + wsum[3]);
        atomicAdd(acc, (double)tot);
        __threadfence();
        int done = atomicAdd(cnt2, 1);
        if (done == (int)gridDim.x - 1) {
            __threadfence();
            double v = atomicAdd(acc, 0.0);   // coherent read after all adds
            out[LOSS_OFF] = (float)(2.0 * v / 8388608.0);
        }
    }
}

extern "C" void kernel_launch(void* const* d_in, const int* in_sizes, int n_in,
                              void* d_out, int out_size, void* d_ws, size_t ws_size,
                              hipStream_t stream) {
    (void)in_sizes; (void)n_in; (void)out_size;
    const float* z  = (const float*)d_in[0];
    const float* cb = (const float*)d_in[1];
    float* out = (float*)d_out;
    char* ws = (char*)d_ws;

    size_t off = 0;
    ushort_t* zsw  = (ushort_t*)(ws + off); off += 16777216;   // bf16 swizzled z
    ushort_t* cbsw = (ushort_t*)(ws + off); off += 4194304;    // bf16 swizzled codebook
    float* ztf = nullptr;
    const size_t ZTF_BYTES = 33554432;                          // fp32 transposed z
    const size_t SURV_BYTES = (size_t)N_ROWS * 4 * CAP_Q * 8;   // int2 lists (46 MB)
    const size_t TAIL = SURV_BYTES + 524288 + 131072 + 64;
    if (ws_size >= off + ZTF_BYTES + TAIL) { ztf = (float*)(ws + off); off += ZTF_BYTES; }
    int2* surv = (int2*)(ws + off); off += SURV_BYTES;
    int* cnt  = (int*)(ws + off); off += 524288;               // [n][quarter]
    int* idxi = (int*)(ws + off); off += 131072;
    double* acc = (double*)(ws + off); off += 8;
    int* cnt2 = (int*)(ws + off);

    k_prep<<<3072, 256, 0, stream>>>(z, cb, zsw, cbsw, ztf, cnt, cnt2, acc);
    k_screen<<<512, 512, 0, stream>>>(zsw, cbsw, surv, cnt);
    k_refine<<<8192, 256, 0, stream>>>(z, ztf, cb, surv, cnt, idxi, out + IDX_OFF);
    k_gather<<<8192 / 16, 256, 0, stream>>>(z, cb, idxi, out, acc, cnt2);
}

// Round 7
// 359.203 us; speedup vs baseline: 1.7055x; 1.7055x over previous
//
#include <hip/hip_runtime.h>
#include <hip/hip_bf16.h>
#include <stdint.h>
#include <stddef.h>

typedef unsigned short ushort_t;
typedef unsigned int uint_t;

typedef __attribute__((ext_vector_type(8))) short short8;
typedef __attribute__((ext_vector_type(4))) float floatx4;
typedef __attribute__((ext_vector_type(16))) float floatx16;
typedef __attribute__((ext_vector_type(4))) uint_t uintx4;

#define N_ROWS 32768
#define K_ENT  8192
#define CDIM   256
#define OUT_ELEMS 8388608
#define LOSS_OFF  8388608
#define IDX_OFF   8388609
// Per-(row, k-quarter) survivor list capacity. Measured (r8): single-pass
// running-max appends are ~20 per quarter; CAP_Q=44 puts overflow at ~1e-6.
#define CAP_Q  44
// Margin: covers bf16 rounding of z,c + reference fp32 quantization ulp(256).
// Refine re-filters stored candidates against the FINAL row max (max of stored
// vals), reproducing the two-phase survivor set. Accumulation order (s=0..15
// per tile) is unchanged from R4.
#define MARGIN    2.0e-4f

// RNE float -> bf16 bits
__device__ __forceinline__ ushort_t f2bf(float f) {
    uint_t x = __float_as_uint(f);
    uint_t r = (x + 0x7fffu + ((x >> 16) & 1u)) >> 16;
    return (ushort_t)r;
}

// Swizzled layout for mfma_32x32x16 fragments: element (row, c) lives at
//   (row>>5)*8192 + (c>>4)*512 + ((c>>3)&1)*256 + (row&31)*8 + (c&7)   [ushort idx]
// -> fragment load for k-step s (lane l: row r0+(l&31), dims s*16+(l>>5)*8, 16 B)
//    is one contiguous 1 KiB per (rowgroup, s); a 32-ent tile is 16 KB contiguous
//    and LINEAR -> global_load_lds(16B) staging works with a linear LDS dest.

__device__ __forceinline__ void gload_lds16(const ushort_t* g, ushort_t* s) {
    __builtin_amdgcn_global_load_lds(
        (__attribute__((address_space(1))) void*)(g),
        (__attribute__((address_space(3))) void*)(s), 16, 0, 0);
}

// Fused prep: blocks [0,2048) transpose z -> swizzled bf16 (+ fp32 ztf copy);
// blocks [2048,3072) pack codebook -> swizzled bf16 and init cnt/cnt2/acc.
__global__ __launch_bounds__(256) void k_prep(const float* __restrict__ zin,
                                              const float* __restrict__ cb,
                                              ushort_t* __restrict__ zsw,
                                              ushort_t* __restrict__ cbsw,
                                              float* __restrict__ ztf,
                                              int* __restrict__ cnt,
                                              int* __restrict__ cnt2,
                                              double* __restrict__ acc) {
    int bid = blockIdx.x;
    if (bid >= 2048) {
        int t = (bid - 2048) * 256 + threadIdx.x;   // 262,144 items
        if (t < N_ROWS * 4) cnt[t] = 0;
        if (t == 0) { *acc = 0.0; *cnt2 = 0; }
        int ent = t >> 5;
        int c0  = (t & 31) << 3;
        const float* p = cb + (size_t)ent * CDIM + c0;
        floatx4 f0 = *(const floatx4*)p;
        floatx4 f1 = *(const floatx4*)(p + 4);
        uintx4 pk;
        pk[0] = (uint_t)f2bf(f0[0]) | ((uint_t)f2bf(f0[1]) << 16);
        pk[1] = (uint_t)f2bf(f0[2]) | ((uint_t)f2bf(f0[3]) << 16);
        pk[2] = (uint_t)f2bf(f1[0]) | ((uint_t)f2bf(f1[1]) << 16);
        pk[3] = (uint_t)f2bf(f1[2]) | ((uint_t)f2bf(f1[3]) << 16);
        int idx = (ent >> 5) * 8192 + (c0 >> 4) * 512 + ((c0 >> 3) & 1) * 256 + (ent & 31) * 8;
        *(uintx4*)(cbsw + idx) = pk;
        return;
    }
    __shared__ float lds[64][65];
    int c0 = (bid & 3) << 6;
    int s0 = ((bid >> 2) & 63) << 6;
    int b  = bid >> 8;
    int tid = threadIdx.x;
    int j = tid & 63, ib = tid >> 6;
    const float* zb = zin + ((size_t)b << 20);
#pragma unroll
    for (int rr = 0; rr < 16; ++rr) {
        int i = rr * 4 + ib;                       // c-local
        lds[i][j] = zb[(size_t)(c0 + i) * 4096 + s0 + j];   // coalesced over j
    }
    __syncthreads();
#pragma unroll
    for (int it = 0; it < 2; ++it) {
        int item = it * 256 + tid;                 // 512 items: (s-local, c-chunk)
        int sl = item >> 3;
        int ch = item & 7;
        int row = (b << 12) + s0 + sl;             // n
        int cg  = c0 + ch * 8;
        uintx4 pk;
        floatx4 f0, f1;
#pragma unroll
        for (int q = 0; q < 4; ++q) {
            float a = lds[ch * 8 + 2 * q][sl];
            float bqv = lds[ch * 8 + 2 * q + 1][sl];
            pk[q] = (uint_t)f2bf(a) | ((uint_t)f2bf(bqv) << 16);
        }
#pragma unroll
        for (int q = 0; q < 4; ++q) {
            f0[q] = lds[ch * 8 + q][sl];
            f1[q] = lds[ch * 8 + 4 + q][sl];
        }
        int idx = (row >> 5) * 8192 + (cg >> 4) * 512 + ((cg >> 3) & 1) * 256 + (row & 31) * 8;
        *(uintx4*)(zsw + idx) = pk;
        if (ztf) {
            *(floatx4*)(ztf + (size_t)row * 256 + cg) = f0;
            *(floatx4*)(ztf + (size_t)row * 256 + cg + 4) = f1;
        }
    }
}

// Per-tile max-reduce + survivor append, ATOMIC-FREE (R4) + __any skip: each
// (row, quarter) list is written only by lane l and partner l^32 of ONE wave;
// slot allocation in-wave (popc + shfl_xor(32)); cnt written once at kernel
// end. Stores fire-and-forget. In R7 this runs one tile BEHIND the MFMA
// stream (acc double-buffer) so its VALU hides in the matrix-pipe shadow and
// its stores are ~600+ cycles old at the barrier drain.
// C/D layout (32x32x16): col(z-row)=lane&31, ent=(r&3)+8*(r>>2)+4*(l>>5).
__device__ __forceinline__ void screen_emit(const floatx16& acc, float& rmx,
                                            int& cur, int hi, int2* slist,
                                            int ent0) {
    float t0 = fmaxf(fmaxf(acc[0], acc[1]), fmaxf(acc[2], acc[3]));
    float t1 = fmaxf(fmaxf(acc[4], acc[5]), fmaxf(acc[6], acc[7]));
    float t2 = fmaxf(fmaxf(acc[8], acc[9]), fmaxf(acc[10], acc[11]));
    float t3 = fmaxf(fmaxf(acc[12], acc[13]), fmaxf(acc[14], acc[15]));
    float mxo = fmaxf(fmaxf(t0, t1), fmaxf(t2, t3));     // own-16 max
    float mx = fmaxf(mxo, __shfl_xor(mxo, 32));          // full-row tile max
    float rm = fmaxf(rmx, mx);
    rmx = rm;
    float thr = rm - MARGIN;
    if (__any(mxo >= thr)) {
        uint_t mask = 0u;
#pragma unroll
        for (int r = 0; r < 16; ++r)
            if (acc[r] >= thr) mask |= (1u << r);
        int p  = __popc(mask);
        int pp = __shfl_xor(p, 32);       // partner lane's count
        int s  = cur + (hi ? pp : 0);     // low-lane slots first
        cur += p + pp;                    // symmetric -> equal in partners
        if (mask) {
#pragma unroll
            for (int r = 0; r < 16; ++r) {
                if (mask & (1u << r)) {
                    if (s < CAP_Q)
                        slist[s] = make_int2(ent0 + (r & 3) + 8 * (r >> 2),
                                             __float_as_int(acc[r]));
                    ++s;
                }
            }
        }
    }
}

// SINGLE-PASS bf16 MFMA screen, 32x32x16, entries on the accumulator register
// axis, z-rows on the lane axis. ROUND 7: R4 geometry (32 rows/wave, 1024
// blocks, 32 KB dbuf LDS, ~12 waves/CU) + EMIT PIPELINED BY ONE TILE. acc is
// double-buffered (accA even tiles, accB odd tiles; static names — no dynamic
// indexing); emit(t-1) sits in the same scheduling region as compute(t)'s
// MFMA issue stream, so its ~150 VALU ops hide in the 512-cycle matrix shadow
// and its stores issue long before the barrier drain. Emit order eA(0), eB(1),
// eA(2), ... is exactly R4's sequence -> survivor set and cnt bit-identical.
__global__ __launch_bounds__(256, 4) void k_screen(const ushort_t* __restrict__ zsw,
                                                   const ushort_t* __restrict__ cbsw,
                                                   int2* __restrict__ surv,
                                                   int* __restrict__ cnt) {
    __shared__ ushort_t bt[2][8192];    // 2 x 16 KB B tiles (32 ents each, linear)
    int tid = threadIdx.x;              // 0..255
    int w = tid >> 6, l = tid & 63;
    int bid = blockIdx.x;
    int q  = bid & 3;                   // k-quarter
    int RB = (bid >> 2) * 128;          // row base; wave w owns rows [RB+w*32, +32)
    int n = RB + w * 32 + (l & 31);     // this lane's z-row
    int cidx = n * 4 + q;
    int2* slist = surv + (size_t)cidx * CAP_Q;
    int tile0 = q * 64;                 // first 32-ent tile of this quarter
    int hi = l & 32;

    // stage tile t into buffer b (16 KB = 256 threads x 16 B x 4)
    auto stage = [&](int t, int b) {
        const ushort_t* gs = cbsw + (size_t)(tile0 + t) * 8192;
#pragma unroll
        for (int j = 0; j < 4; ++j)
            gload_lds16(gs + j * 2048 + tid * 8, &bt[b][j * 2048 + w * 512]);
    };

    // prologue: stage tile 0 into buf 0
    stage(0, 0);

    // z fragments (B operand: rows on lanes, 16 k-steps) held in regs all kernel
    short8 zfr[16];
    {
        const ushort_t* pz = zsw + (size_t)((RB >> 5) + w) * 8192 + l * 8;
#pragma unroll
        for (int s = 0; s < 16; ++s)
            zfr[s] = *(const short8*)(pz + s * 512);
    }
    __syncthreads();

    float rmx = -3.0e38f;               // running row max (same in both halves)
    int cur = 0;                        // running survivor count for this row
    int esub = (l >> 5) * 4;            // C/D ent = (r&3) + 8*(r>>2) + 4*(l>>5)

    floatx16 accA, accB;
    auto compute = [&](floatx16& acc, int b) {
        const ushort_t* bb = &bt[b][l * 8];
#pragma unroll
        for (int i = 0; i < 16; ++i) acc[i] = 0.f;
#pragma unroll
        for (int s = 0; s < 16; ++s) {
            short8 a = *(const short8*)(bb + s * 512);   // codebook frag (A: ents)
            acc = __builtin_amdgcn_mfma_f32_32x32x16_bf16(a, zfr[s], acc, 0, 0, 0);
        }
    };
    auto ent_of = [&](int t) { return (tile0 + t) * 32 + esub; };

    // t = 0: compute A, nothing to emit yet
    stage(1, 1);
    __builtin_amdgcn_s_setprio(1);
    compute(accA, 0);
    __builtin_amdgcn_s_setprio(0);
    __syncthreads();

    for (int t = 1; t < 63; t += 2) {
        // odd tile t: compute B, emit A(t-1) in B's MFMA shadow
        stage(t + 1, (t + 1) & 1);
        __builtin_amdgcn_s_setprio(1);
        compute(accB, t & 1);
        screen_emit(accA, rmx, cur, hi, slist, ent_of(t - 1));
        __builtin_amdgcn_s_setprio(0);
        __syncthreads();
        // even tile t+1: compute A, emit B(t) in A's MFMA shadow
        stage(t + 2, t & 1);
        __builtin_amdgcn_s_setprio(1);
        compute(accA, (t + 1) & 1);
        screen_emit(accB, rmx, cur, hi, slist, ent_of(t));
        __builtin_amdgcn_s_setprio(0);
        __syncthreads();
    }
    // tail: tile 63 (staged into buf 1 by the last loop iteration)
    __builtin_amdgcn_s_setprio(1);
    compute(accB, 1);
    screen_emit(accA, rmx, cur, hi, slist, ent_of(62));
    __builtin_amdgcn_s_setprio(0);
    screen_emit(accB, rmx, cur, hi, slist, ent_of(63));

    if (!hi) cnt[cidx] = cur;           // one writer per (row, quarter)
}

// Exact fp32 refine: gather <=176 stored (ent, bf16-dot) candidates from the 4
// quarter lists, filter by val >= finalmax - MARGIN (finalmax = max stored val;
// the record-setter always self-appends), then fp32 dots for the ~1-3 passing
// candidates. Serial fmaf order unchanged, so idx semantics are unchanged.
// Overflow (~1e-6 probability) -> 4-chain fast full-scan fallback.
__global__ __launch_bounds__(256) void k_refine(const float* __restrict__ zin,
                                                const float* __restrict__ ztf,
                                                const float* __restrict__ cb,
                                                const int2* __restrict__ surv,
                                                const int* __restrict__ cnt,
                                                int* __restrict__ idxi,
                                                float* __restrict__ idxf) {
    __shared__ float zr[4][256];
    int w = threadIdx.x >> 6, l = threadIdx.x & 63;
    int n = blockIdx.x * 4 + w;
    if (ztf) {
        const float* zrow = ztf + (size_t)n * 256;
#pragma unroll
        for (int i = 0; i < 4; ++i)
            zr[w][l + 64 * i] = zrow[l + 64 * i];          // coalesced
    } else {
        int b = n >> 12, s = n & 4095;
        const float* zb = zin + ((size_t)b << 20) + s;
#pragma unroll
        for (int i = 0; i < 4; ++i)
            zr[w][l + 64 * i] = zb[(size_t)(l + 64 * i) << 12];
    }
    __syncthreads();
    const float* z = zr[w];
    float zn = 0.f;
    for (int c = 0; c < 256; ++c) zn = fmaf(z[c], z[c], zn);

    int c0 = cnt[n * 4 + 0], c1 = cnt[n * 4 + 1];
    int c2 = cnt[n * 4 + 2], c3 = cnt[n * 4 + 3];
    int m = c0 + c1 + c2 + c3;
    bool ok = (c0 <= CAP_Q) && (c1 <= CAP_Q) && (c2 <= CAP_Q) && (c3 <= CAP_Q) && (m >= 1);
    float bu = 3.0e38f;
    int bk = 0x7fffffff;
    if (ok) {
        int myk[3]; float myv[3]; int nc = 0;
        float vmax = -3.0e38f;
        for (int i = l; i < m; i += 64) {
            int qq, s;
            if (i < c0)            { qq = 0; s = i; }
            else if (i < c0 + c1)  { qq = 1; s = i - c0; }
            else if (i < c0 + c1 + c2) { qq = 2; s = i - c0 - c1; }
            else                   { qq = 3; s = i - c0 - c1 - c2; }
            int2 kv = surv[(n * 4 + qq) * CAP_Q + s];
            myk[nc] = kv.x;
            myv[nc] = __int_as_float(kv.y);
            vmax = fmaxf(vmax, myv[nc]);
            ++nc;
        }
#pragma unroll
        for (int msk = 1; msk < 64; msk <<= 1)
            vmax = fmaxf(vmax, __shfl_xor(vmax, msk));
        float fthr = vmax - MARGIN;
        for (int jj = 0; jj < nc; ++jj) {
            if (myv[jj] >= fthr) {
                int k = myk[jj];
                const float* cr = cb + (size_t)k * 256;
                float d = 0.f;
                for (int c = 0; c < 256; c += 4) {
                    floatx4 wv = *(const floatx4*)(cr + c);
                    d = fmaf(z[c], wv[0], d);
                    d = fmaf(z[c + 1], wv[1], d);
                    d = fmaf(z[c + 2], wv[2], d);
                    d = fmaf(z[c + 3], wv[3], d);
                }
                float u = zn - 2.0f * d;
                if (u < bu || (u == bu && k < bk)) { bu = u; bk = k; }
            }
        }
    } else {
        // fallback: exact scan of all K with 4 independent chains (cold path)
        for (int kb = l; kb < K_ENT; kb += 256) {
            const float* p0 = cb + (size_t)(kb)       * 256;
            const float* p1 = cb + (size_t)(kb + 64)  * 256;
            const float* p2 = cb + (size_t)(kb + 128) * 256;
            const float* p3 = cb + (size_t)(kb + 192) * 256;
            float d0 = 0.f, d1 = 0.f, d2 = 0.f, d3 = 0.f;
            for (int c = 0; c < 256; c += 4) {
                floatx4 w0 = *(const floatx4*)(p0 + c);
                floatx4 w1 = *(const floatx4*)(p1 + c);
                floatx4 w2 = *(const floatx4*)(p2 + c);
                floatx4 w3 = *(const floatx4*)(p3 + c);
#pragma unroll
                for (int j = 0; j < 4; ++j) {
                    d0 = fmaf(z[c + j], w0[j], d0);
                    d1 = fmaf(z[c + j], w1[j], d1);
                    d2 = fmaf(z[c + j], w2[j], d2);
                    d3 = fmaf(z[c + j], w3[j], d3);
                }
            }
            float u0 = zn - 2.0f * d0, u1 = zn - 2.0f * d1;
            float u2 = zn - 2.0f * d2, u3 = zn - 2.0f * d3;
            // ascending k order preserves first-index tie-break
            if (u0 < bu) { bu = u0; bk = kb; }
            if (u1 < bu) { bu = u1; bk = kb + 64; }
            if (u2 < bu) { bu = u2; bk = kb + 128; }
            if (u3 < bu) { bu = u3; bk = kb + 192; }
        }
    }
#pragma unroll
    for (int msk = 1; msk < 64; msk <<= 1) {
        float ou = __shfl_xor(bu, msk);
        int   ok2 = __shfl_xor(bk, msk);
        if (ou < bu || (ou == bu && ok2 < bk)) { bu = ou; bk = ok2; }
    }
    if (l == 0) { idxi[n] = bk; idxf[n] = (float)bk; }
}

// Gather z_q + loss (coalesced codebook reads via LDS transpose), with fused
// last-block loss finalization (device-scope atomics + threadfence).
__global__ __launch_bounds__(256) void k_gather(const float* __restrict__ zin,
                                                const float* __restrict__ cb,
                                                const int* __restrict__ idxi,
                                                float* __restrict__ out,
                                                double* __restrict__ acc,
                                                int* __restrict__ cnt2) {
    __shared__ float tile[64][65];
    __shared__ int lk[64];
    __shared__ float wsum[4];
    int t = threadIdx.x;
    int blk = blockIdx.x;
    int b = blk >> 6;
    int s0 = (blk & 63) << 6;
    int n0 = (b << 12) + s0;
    if (t < 64) lk[t] = idxi[n0 + t];
    __syncthreads();
    int wv = t >> 6, ln = t & 63;
    float ls = 0.f;
#pragma unroll
    for (int ct = 0; ct < 4; ++ct) {
        int c0 = ct << 6;
#pragma unroll
        for (int i = 0; i < 16; ++i) {
            int sl = (wv << 4) + i;
            tile[sl][ln] = cb[(size_t)lk[sl] * 256 + c0 + ln];   // 256 B coalesced
        }
        __syncthreads();
        const float* zb = zin + ((size_t)b << 20);
        float* ob = out + ((size_t)b << 20);
#pragma unroll
        for (int j = 0; j < 16; ++j) {
            int cl = (wv << 4) + j;
            size_t o = (size_t)(c0 + cl) * 4096 + s0 + ln;
            float v = tile[ln][cl];       // stride-65: 2-way bank alias (free)
            float zv = zb[o];
            ob[o] = v;
            float d = v - zv;
            ls = fmaf(d, d, ls);
        }
        __syncthreads();
    }
#pragma unroll
    for (int msk = 1; msk < 64; msk <<= 1) ls += __shfl_xor(ls, msk);
    if (ln == 0) wsum[wv] = ls;
    __syncthreads();
    if (t == 0) {
        float tot = (wsum[0] + wsum[1]) + (wsum[2] + wsum[3]);
        atomicAdd(acc, (double)tot);
        __threadfence();
        int done = atomicAdd(cnt2, 1);
        if (done == (int)gridDim.x - 1) {
            __threadfence();
            double v = atomicAdd(acc, 0.0);   // coherent read after all adds
            out[LOSS_OFF] = (float)(2.0 * v / 8388608.0);
        }
    }
}

extern "C" void kernel_launch(void* const* d_in, const int* in_sizes, int n_in,
                              void* d_out, int out_size, void* d_ws, size_t ws_size,
                              hipStream_t stream) {
    (void)in_sizes; (void)n_in; (void)out_size;
    const float* z  = (const float*)d_in[0];
    const float* cb = (const float*)d_in[1];
    float* out = (float*)d_out;
    char* ws = (char*)d_ws;

    size_t off = 0;
    ushort_t* zsw  = (ushort_t*)(ws + off); off += 16777216;   // bf16 swizzled z
    ushort_t* cbsw = (ushort_t*)(ws + off); off += 4194304;    // bf16 swizzled codebook
    float* ztf = nullptr;
    const size_t ZTF_BYTES = 33554432;                          // fp32 transposed z
    const size_t SURV_BYTES = (size_t)N_ROWS * 4 * CAP_Q * 8;   // int2 lists (46 MB)
    const size_t TAIL = SURV_BYTES + 524288 + 131072 + 64;
    if (ws_size >= off + ZTF_BYTES + TAIL) { ztf = (float*)(ws + off); off += ZTF_BYTES; }
    int2* surv = (int2*)(ws + off); off += SURV_BYTES;
    int* cnt  = (int*)(ws + off); off += 524288;               // [n][quarter]
    int* idxi = (int*)(ws + off); off += 131072;
    double* acc = (double*)(ws + off); off += 8;
    int* cnt2 = (int*)(ws + off);

    k_prep<<<3072, 256, 0, stream>>>(z, cb, zsw, cbsw, ztf, cnt, cnt2, acc);
    k_screen<<<1024, 256, 0, stream>>>(zsw, cbsw, surv, cnt);
    k_refine<<<8192, 256, 0, stream>>>(z, ztf, cb, surv, cnt, idxi, out + IDX_OFF);
    k_gather<<<8192 / 16, 256, 0, stream>>>(z, cb, idxi, out, acc, cnt2);
}

// Round 8
// 336.216 us; speedup vs baseline: 1.8221x; 1.0684x over previous
//
#include <hip/hip_runtime.h>
#include <hip/hip_bf16.h>
#include <stdint.h>
#include <stddef.h>

typedef unsigned short ushort_t;
typedef unsigned int uint_t;

typedef __attribute__((ext_vector_type(8))) short short8;
typedef __attribute__((ext_vector_type(4))) float floatx4;
typedef __attribute__((ext_vector_type(16))) float floatx16;
typedef __attribute__((ext_vector_type(4))) uint_t uintx4;

#define N_ROWS 32768
#define K_ENT  8192
#define CDIM   256
#define OUT_ELEMS 8388608
#define LOSS_OFF  8388608
#define IDX_OFF   8388609
// Per-(row, k-quarter) survivor list capacity. Measured (r8): single-pass
// running-max appends are ~20 per quarter; CAP_Q=44 puts overflow at ~1e-6.
#define CAP_Q  44
// Margin: covers bf16 rounding of z,c + reference fp32 quantization ulp(256).
// Refine re-filters stored candidates against the FINAL row max (max of stored
// vals), reproducing the two-phase survivor set. Accumulation order (s=0..15
// per tile) is unchanged from R4 (ZERO-C first MFMA is bitwise identical).
#define MARGIN    2.0e-4f

// RNE float -> bf16 bits
__device__ __forceinline__ ushort_t f2bf(float f) {
    uint_t x = __float_as_uint(f);
    uint_t r = (x + 0x7fffu + ((x >> 16) & 1u)) >> 16;
    return (ushort_t)r;
}

// Swizzled layout for mfma_32x32x16 fragments: element (row, c) lives at
//   (row>>5)*8192 + (c>>4)*512 + ((c>>3)&1)*256 + (row&31)*8 + (c&7)   [ushort idx]
// -> fragment load for k-step s (lane l: row r0+(l&31), dims s*16+(l>>5)*8, 16 B)
//    is one contiguous 1 KiB per (rowgroup, s); a 32-ent tile is 16 KB contiguous
//    and LINEAR -> global_load_lds(16B) staging works with a linear LDS dest.

__device__ __forceinline__ void gload_lds16(const ushort_t* g, ushort_t* s) {
    __builtin_amdgcn_global_load_lds(
        (__attribute__((address_space(1))) void*)(g),
        (__attribute__((address_space(3))) void*)(s), 16, 0, 0);
}

// Fused prep: blocks [0,2048) transpose z -> swizzled bf16 (+ fp32 ztf copy);
// blocks [2048,3072) pack codebook -> swizzled bf16 AND compute per-entry
// squared norms cn[ent] (used by refine's loss: ||c-z||^2 = cn + (zn - 2d)).
// cnt zero-init removed: k_screen writes every cnt slot unconditionally (R4+).
__global__ __launch_bounds__(256) void k_prep(const float* __restrict__ zin,
                                              const float* __restrict__ cb,
                                              ushort_t* __restrict__ zsw,
                                              ushort_t* __restrict__ cbsw,
                                              float* __restrict__ ztf,
                                              float* __restrict__ cn) {
    int bid = blockIdx.x;
    if (bid >= 2048) {
        int t = (bid - 2048) * 256 + threadIdx.x;   // 262,144 items
        int ent = t >> 5;
        int c0  = (t & 31) << 3;
        const float* p = cb + (size_t)ent * CDIM + c0;
        floatx4 f0 = *(const floatx4*)p;
        floatx4 f1 = *(const floatx4*)(p + 4);
        uintx4 pk;
        pk[0] = (uint_t)f2bf(f0[0]) | ((uint_t)f2bf(f0[1]) << 16);
        pk[1] = (uint_t)f2bf(f0[2]) | ((uint_t)f2bf(f0[3]) << 16);
        pk[2] = (uint_t)f2bf(f1[0]) | ((uint_t)f2bf(f1[1]) << 16);
        pk[3] = (uint_t)f2bf(f1[2]) | ((uint_t)f2bf(f1[3]) << 16);
        int idx = (ent >> 5) * 8192 + (c0 >> 4) * 512 + ((c0 >> 3) & 1) * 256 + (ent & 31) * 8;
        *(uintx4*)(cbsw + idx) = pk;
        // entry squared-norm: 8-elem partial + 32-lane-group shuffle reduce
        float pn = 0.f;
#pragma unroll
        for (int qq = 0; qq < 4; ++qq) pn = fmaf(f0[qq], f0[qq], pn);
#pragma unroll
        for (int qq = 0; qq < 4; ++qq) pn = fmaf(f1[qq], f1[qq], pn);
#pragma unroll
        for (int m = 1; m < 32; m <<= 1) pn += __shfl_xor(pn, m);
        if ((t & 31) == 0) cn[ent] = pn;
        return;
    }
    __shared__ float lds[64][65];
    int c0 = (bid & 3) << 6;
    int s0 = ((bid >> 2) & 63) << 6;
    int b  = bid >> 8;
    int tid = threadIdx.x;
    int j = tid & 63, ib = tid >> 6;
    const float* zb = zin + ((size_t)b << 20);
#pragma unroll
    for (int rr = 0; rr < 16; ++rr) {
        int i = rr * 4 + ib;                       // c-local
        lds[i][j] = zb[(size_t)(c0 + i) * 4096 + s0 + j];   // coalesced over j
    }
    __syncthreads();
#pragma unroll
    for (int it = 0; it < 2; ++it) {
        int item = it * 256 + tid;                 // 512 items: (s-local, c-chunk)
        int sl = item >> 3;
        int ch = item & 7;
        int row = (b << 12) + s0 + sl;             // n
        int cg  = c0 + ch * 8;
        uintx4 pk;
        floatx4 f0, f1;
#pragma unroll
        for (int q = 0; q < 4; ++q) {
            float a = lds[ch * 8 + 2 * q][sl];
            float bqv = lds[ch * 8 + 2 * q + 1][sl];
            pk[q] = (uint_t)f2bf(a) | ((uint_t)f2bf(bqv) << 16);
        }
#pragma unroll
        for (int q = 0; q < 4; ++q) {
            f0[q] = lds[ch * 8 + q][sl];
            f1[q] = lds[ch * 8 + 4 + q][sl];
        }
        int idx = (row >> 5) * 8192 + (cg >> 4) * 512 + ((cg >> 3) & 1) * 256 + (row & 31) * 8;
        *(uintx4*)(zsw + idx) = pk;
        if (ztf) {
            *(floatx4*)(ztf + (size_t)row * 256 + cg) = f0;
            *(floatx4*)(ztf + (size_t)row * 256 + cg + 4) = f1;
        }
    }
}

// Per-tile max-reduce + survivor append, ATOMIC-FREE + __any skip (R4/R5):
// each (row, quarter) list is written only by lane l and partner l^32 of ONE
// wave; slot allocation in-wave (popc + shfl_xor(32)); cnt written once at
// kernel end. Runs one tile BEHIND the MFMA stream (R7 acc double-buffer).
// C/D layout (32x32x16): col(z-row)=lane&31, ent=(r&3)+8*(r>>2)+4*(l>>5).
__device__ __forceinline__ void screen_emit(const floatx16& acc, float& rmx,
                                            int& cur, int hi, int2* slist,
                                            int ent0) {
    float t0 = fmaxf(fmaxf(acc[0], acc[1]), fmaxf(acc[2], acc[3]));
    float t1 = fmaxf(fmaxf(acc[4], acc[5]), fmaxf(acc[6], acc[7]));
    float t2 = fmaxf(fmaxf(acc[8], acc[9]), fmaxf(acc[10], acc[11]));
    float t3 = fmaxf(fmaxf(acc[12], acc[13]), fmaxf(acc[14], acc[15]));
    float mxo = fmaxf(fmaxf(t0, t1), fmaxf(t2, t3));     // own-16 max
    float mx = fmaxf(mxo, __shfl_xor(mxo, 32));          // full-row tile max
    float rm = fmaxf(rmx, mx);
    rmx = rm;
    float thr = rm - MARGIN;
    if (__any(mxo >= thr)) {
        uint_t mask = 0u;
#pragma unroll
        for (int r = 0; r < 16; ++r)
            if (acc[r] >= thr) mask |= (1u << r);
        int p  = __popc(mask);
        int pp = __shfl_xor(p, 32);       // partner lane's count
        int s  = cur + (hi ? pp : 0);     // low-lane slots first
        cur += p + pp;                    // symmetric -> equal in partners
        if (mask) {
#pragma unroll
            for (int r = 0; r < 16; ++r) {
                if (mask & (1u << r)) {
                    if (s < CAP_Q)
                        slist[s] = make_int2(ent0 + (r & 3) + 8 * (r >> 2),
                                             __float_as_int(acc[r]));
                    ++s;
                }
            }
        }
    }
}

// SINGLE-PASS bf16 MFMA screen, 32x32x16, entries on the accumulator register
// axis, z-rows on the lane axis. ROUND 8: R7 pipelined-emit structure +
// (a) persistent ZERO accumulator: the first MFMA of each tile takes C=zacc
// (16 always-zero regs) instead of 32 v_mov zero-inits per kt — D bitwise
// identical; (b) staging via one running global pointer (+16 KB/stage)
// instead of recomputed 64-bit addresses.
__global__ __launch_bounds__(256, 4) void k_screen(const ushort_t* __restrict__ zsw,
                                                   const ushort_t* __restrict__ cbsw,
                                                   int2* __restrict__ surv,
                                                   int* __restrict__ cnt) {
    __shared__ ushort_t bt[2][8192];    // 2 x 16 KB B tiles (32 ents each, linear)
    int tid = threadIdx.x;              // 0..255
    int w = tid >> 6, l = tid & 63;
    int bid = blockIdx.x;
    int q  = bid & 3;                   // k-quarter
    int RB = (bid >> 2) * 128;          // row base; wave w owns rows [RB+w*32, +32)
    int n = RB + w * 32 + (l & 31);     // this lane's z-row
    int cidx = n * 4 + q;
    int2* slist = surv + (size_t)cidx * CAP_Q;
    int tile0 = q * 64;                 // first 32-ent tile of this quarter
    int hi = l & 32;

    // running stage pointer: tiles are staged strictly in order 0..63
    const ushort_t* gsp = cbsw + (size_t)tile0 * 8192 + tid * 8;
    auto stage = [&](ushort_t* ld) {    // ld = &bt[buf][w*512]
#pragma unroll
        for (int j = 0; j < 4; ++j)
            gload_lds16(gsp + j * 2048, ld + j * 2048);
        gsp += 8192;                    // next 16 KB tile
    };

    stage(&bt[0][w * 512]);             // tile 0 -> buf 0

    // z fragments (B operand: rows on lanes, 16 k-steps) held in regs all kernel
    short8 zfr[16];
    {
        const ushort_t* pz = zsw + (size_t)((RB >> 5) + w) * 8192 + l * 8;
#pragma unroll
        for (int s = 0; s < 16; ++s)
            zfr[s] = *(const short8*)(pz + s * 512);
    }
    __syncthreads();

    float rmx = -3.0e38f;               // running row max (same in both halves)
    int cur = 0;                        // running survivor count for this row
    int esub = (l >> 5) * 4;            // C/D ent = (r&3) + 8*(r>>2) + 4*(l>>5)

    floatx16 zacc;                      // persistent zero C-input
#pragma unroll
    for (int i = 0; i < 16; ++i) zacc[i] = 0.f;

    floatx16 accA, accB;
    auto compute = [&](floatx16& acc, int b) {
        const ushort_t* bb = &bt[b][l * 8];
        short8 a0 = *(const short8*)(bb);
        acc = __builtin_amdgcn_mfma_f32_32x32x16_bf16(a0, zfr[0], zacc, 0, 0, 0);
#pragma unroll
        for (int s = 1; s < 16; ++s) {
            short8 a = *(const short8*)(bb + s * 512);   // codebook frag (A: ents)
            acc = __builtin_amdgcn_mfma_f32_32x32x16_bf16(a, zfr[s], acc, 0, 0, 0);
        }
    };
    auto ent_of = [&](int t) { return (tile0 + t) * 32 + esub; };

    // t = 0: compute A, nothing to emit yet
    stage(&bt[1][w * 512]);             // tile 1 -> buf 1
    __builtin_amdgcn_s_setprio(1);
    compute(accA, 0);
    __builtin_amdgcn_s_setprio(0);
    __syncthreads();

    for (int t = 1; t < 63; t += 2) {
        // odd tile t: compute B, emit A(t-1) in B's MFMA shadow
        stage(&bt[0][w * 512]);         // tile t+1 (even) -> buf 0
        __builtin_amdgcn_s_setprio(1);
        compute(accB, 1);
        screen_emit(accA, rmx, cur, hi, slist, ent_of(t - 1));
        __builtin_amdgcn_s_setprio(0);
        __syncthreads();
        // even tile t+1: compute A, emit B(t) in A's MFMA shadow
        stage(&bt[1][w * 512]);         // tile t+2 (odd) -> buf 1
        __builtin_amdgcn_s_setprio(1);
        compute(accA, 0);
        screen_emit(accB, rmx, cur, hi, slist, ent_of(t));
        __builtin_amdgcn_s_setprio(0);
        __syncthreads();
    }
    // tail: tile 63 (staged into buf 1 by the last loop iteration)
    __builtin_amdgcn_s_setprio(1);
    compute(accB, 1);
    screen_emit(accA, rmx, cur, hi, slist, ent_of(62));
    __builtin_amdgcn_s_setprio(0);
    screen_emit(accB, rmx, cur, hi, slist, ent_of(63));

    if (!hi) cnt[cidx] = cur;           // one writer per (row, quarter)
}

// Exact fp32 refine: gather <=176 stored (ent, bf16-dot) candidates from the 4
// quarter lists, filter by val >= finalmax - MARGIN (finalmax = max stored val;
// the record-setter always self-appends), then fp32 dots for the ~1-3 passing
// candidates. Serial fmaf order unchanged, so idx semantics are unchanged.
// ROUND 8: also emits the per-block loss partial: per-row loss = ||c-z||^2 =
// cn[bk] + bu (bu = zn - 2d of the winner, already computed). zn shifts all
// u_k equally so argmin/tie semantics are untouched.
__global__ __launch_bounds__(256) void k_refine(const float* __restrict__ zin,
                                                const float* __restrict__ ztf,
                                                const float* __restrict__ cb,
                                                const int2* __restrict__ surv,
                                                const int* __restrict__ cnt,
                                                int* __restrict__ idxi,
                                                float* __restrict__ idxf,
                                                const float* __restrict__ cn,
                                                float* __restrict__ lossp) {
    __shared__ float zr[4][256];
    __shared__ float lossw[4];
    int w = threadIdx.x >> 6, l = threadIdx.x & 63;
    int n = blockIdx.x * 4 + w;
    if (ztf) {
        const float* zrow = ztf + (size_t)n * 256;
#pragma unroll
        for (int i = 0; i < 4; ++i)
            zr[w][l + 64 * i] = zrow[l + 64 * i];          // coalesced
    } else {
        int b = n >> 12, s = n & 4095;
        const float* zb = zin + ((size_t)b << 20) + s;
#pragma unroll
        for (int i = 0; i < 4; ++i)
            zr[w][l + 64 * i] = zb[(size_t)(l + 64 * i) << 12];
    }
    __syncthreads();
    const float* z = zr[w];
    float zn = 0.f;
    for (int c = 0; c < 256; ++c) zn = fmaf(z[c], z[c], zn);

    int c0 = cnt[n * 4 + 0], c1 = cnt[n * 4 + 1];
    int c2 = cnt[n * 4 + 2], c3 = cnt[n * 4 + 3];
    int m = c0 + c1 + c2 + c3;
    bool ok = (c0 <= CAP_Q) && (c1 <= CAP_Q) && (c2 <= CAP_Q) && (c3 <= CAP_Q) && (m >= 1);
    float bu = 3.0e38f;
    int bk = 0x7fffffff;
    if (ok) {
        int myk[3]; float myv[3]; int nc = 0;
        float vmax = -3.0e38f;
        for (int i = l; i < m; i += 64) {
            int qq, s;
            if (i < c0)            { qq = 0; s = i; }
            else if (i < c0 + c1)  { qq = 1; s = i - c0; }
            else if (i < c0 + c1 + c2) { qq = 2; s = i - c0 - c1; }
            else                   { qq = 3; s = i - c0 - c1 - c2; }
            int2 kv = surv[(n * 4 + qq) * CAP_Q + s];
            myk[nc] = kv.x;
            myv[nc] = __int_as_float(kv.y);
            vmax = fmaxf(vmax, myv[nc]);
            ++nc;
        }
#pragma unroll
        for (int msk = 1; msk < 64; msk <<= 1)
            vmax = fmaxf(vmax, __shfl_xor(vmax, msk));
        float fthr = vmax - MARGIN;
        for (int jj = 0; jj < nc; ++jj) {
            if (myv[jj] >= fthr) {
                int k = myk[jj];
                const float* cr = cb + (size_t)k * 256;
                float d = 0.f;
                for (int c = 0; c < 256; c += 4) {
                    floatx4 wv = *(const floatx4*)(cr + c);
                    d = fmaf(z[c], wv[0], d);
                    d = fmaf(z[c + 1], wv[1], d);
                    d = fmaf(z[c + 2], wv[2], d);
                    d = fmaf(z[c + 3], wv[3], d);
                }
                float u = zn - 2.0f * d;
                if (u < bu || (u == bu && k < bk)) { bu = u; bk = k; }
            }
        }
    } else {
        // fallback: exact scan of all K with 4 independent chains (cold path)
        for (int kb = l; kb < K_ENT; kb += 256) {
            const float* p0 = cb + (size_t)(kb)       * 256;
            const float* p1 = cb + (size_t)(kb + 64)  * 256;
            const float* p2 = cb + (size_t)(kb + 128) * 256;
            const float* p3 = cb + (size_t)(kb + 192) * 256;
            float d0 = 0.f, d1 = 0.f, d2 = 0.f, d3 = 0.f;
            for (int c = 0; c < 256; c += 4) {
                floatx4 w0 = *(const floatx4*)(p0 + c);
                floatx4 w1 = *(const floatx4*)(p1 + c);
                floatx4 w2 = *(const floatx4*)(p2 + c);
                floatx4 w3 = *(const floatx4*)(p3 + c);
#pragma unroll
                for (int j = 0; j < 4; ++j) {
                    d0 = fmaf(z[c + j], w0[j], d0);
                    d1 = fmaf(z[c + j], w1[j], d1);
                    d2 = fmaf(z[c + j], w2[j], d2);
                    d3 = fmaf(z[c + j], w3[j], d3);
                }
            }
            float u0 = zn - 2.0f * d0, u1 = zn - 2.0f * d1;
            float u2 = zn - 2.0f * d2, u3 = zn - 2.0f * d3;
            // ascending k order preserves first-index tie-break
            if (u0 < bu) { bu = u0; bk = kb; }
            if (u1 < bu) { bu = u1; bk = kb + 64; }
            if (u2 < bu) { bu = u2; bk = kb + 128; }
            if (u3 < bu) { bu = u3; bk = kb + 192; }
        }
    }
#pragma unroll
    for (int msk = 1; msk < 64; msk <<= 1) {
        float ou = __shfl_xor(bu, msk);
        int   ok2 = __shfl_xor(bk, msk);
        if (ou < bu || (ou == bu && ok2 < bk)) { bu = ou; bk = ok2; }
    }
    if (l == 0) {
        idxi[n] = bk;
        idxf[n] = (float)bk;
        lossw[w] = bu + cn[bk];          // per-row loss = ||c_bk - z||^2
    }
    __syncthreads();
    if (threadIdx.x == 0)
        lossp[blockIdx.x] = (lossw[0] + lossw[1]) + (lossw[2] + lossw[3]);
}

// Gather z_q (coalesced codebook reads via LDS transpose). ROUND 8: pure
// gather-scatter — z re-read and per-element loss removed (loss computed in
// refine); block 0 additionally sums the 8192 refine loss partials in double
// and writes the final loss (no atomics / fences / completion counter).
__global__ __launch_bounds__(256) void k_gather(const float* __restrict__ cb,
                                                const int* __restrict__ idxi,
                                                const float* __restrict__ lossp,
                                                float* __restrict__ out) {
    __shared__ float tile[64][65];
    __shared__ int lk[64];
    __shared__ double dsum[4];
    int t = threadIdx.x;
    int blk = blockIdx.x;
    int b = blk >> 6;
    int s0 = (blk & 63) << 6;
    int n0 = (b << 12) + s0;
    if (t < 64) lk[t] = idxi[n0 + t];
    __syncthreads();
    int wv = t >> 6, ln = t & 63;
    float* ob = out + ((size_t)b << 20);
#pragma unroll
    for (int ct = 0; ct < 4; ++ct) {
        int c0 = ct << 6;
#pragma unroll
        for (int i = 0; i < 16; ++i) {
            int sl = (wv << 4) + i;
            tile[sl][ln] = cb[(size_t)lk[sl] * 256 + c0 + ln];   // 256 B coalesced
        }
        __syncthreads();
#pragma unroll
        for (int j = 0; j < 16; ++j) {
            int cl = (wv << 4) + j;
            ob[(size_t)(c0 + cl) * 4096 + s0 + ln] = tile[ln][cl];
        }
        __syncthreads();
    }
    if (blk == 0) {
        double s = 0.0;
        for (int i = t; i < 8192; i += 256) s += (double)lossp[i];
#pragma unroll
        for (int msk = 1; msk < 64; msk <<= 1) s += __shfl_xor(s, msk);
        if (ln == 0) dsum[wv] = s;
        __syncthreads();
        if (t == 0)
            out[LOSS_OFF] = (float)(2.0 * ((dsum[0] + dsum[1]) + (dsum[2] + dsum[3]))
                                    / 8388608.0);
    }
}

extern "C" void kernel_launch(void* const* d_in, const int* in_sizes, int n_in,
                              void* d_out, int out_size, void* d_ws, size_t ws_size,
                              hipStream_t stream) {
    (void)in_sizes; (void)n_in; (void)out_size;
    const float* z  = (const float*)d_in[0];
    const float* cb = (const float*)d_in[1];
    float* out = (float*)d_out;
    char* ws = (char*)d_ws;

    size_t off = 0;
    ushort_t* zsw  = (ushort_t*)(ws + off); off += 16777216;   // bf16 swizzled z
    ushort_t* cbsw = (ushort_t*)(ws + off); off += 4194304;    // bf16 swizzled codebook
    float* ztf = nullptr;
    const size_t ZTF_BYTES = 33554432;                          // fp32 transposed z
    const size_t SURV_BYTES = (size_t)N_ROWS * 4 * CAP_Q * 8;   // int2 lists (46 MB)
    const size_t TAIL = SURV_BYTES + 524288 + 131072 + 32768 + 32768;
    if (ws_size >= off + ZTF_BYTES + TAIL) { ztf = (float*)(ws + off); off += ZTF_BYTES; }
    int2* surv = (int2*)(ws + off); off += SURV_BYTES;
    int* cnt    = (int*)(ws + off); off += 524288;             // [n][quarter]
    int* idxi   = (int*)(ws + off); off += 131072;
    float* cn   = (float*)(ws + off); off += 32768;            // codebook sq-norms
    float* lossp = (float*)(ws + off); off += 32768;           // per-refine-block loss

    k_prep<<<3072, 256, 0, stream>>>(z, cb, zsw, cbsw, ztf, cn);
    k_screen<<<1024, 256, 0, stream>>>(zsw, cbsw, surv, cnt);
    k_refine<<<8192, 256, 0, stream>>>(z, ztf, cb, surv, cnt, idxi, out + IDX_OFF, cn, lossp);
    k_gather<<<8192 / 16, 256, 0, stream>>>(cb, idxi, lossp, out);
}